// Round 4
// baseline (21184.175 us; speedup 1.0000x reference)
//
#include <hip/hip_runtime.h>
#include <math.h>

#define B 64
#define H 1024
#define V 16384
#define T 64
#define NBLK 256
constexpr size_t TBV = (size_t)T * B * V;

typedef __attribute__((ext_vector_type(8))) short bhalf8;
typedef __attribute__((ext_vector_type(16))) float f32x16;

// Truncation split: a = hi + lo, hi = top-16-bits(a); total rep error ~2^-16 rel.
__device__ __forceinline__ void split_trunc(float a, unsigned short& hi, unsigned short& lo) {
    unsigned u = __float_as_uint(a);
    hi = (unsigned short)(u >> 16);
    float hif = __uint_as_float(u & 0xFFFF0000u);
    lo = (unsigned short)(__float_as_uint(a - hif) >> 16);
}

__device__ __forceinline__ void cvt8(const float* f, int4& hv, int4& lv) {
    unsigned h[8], l[8];
#pragma unroll
    for (int j = 0; j < 8; ++j) {
        unsigned u = __float_as_uint(f[j]);
        h[j] = u >> 16;
        float hif = __uint_as_float(u & 0xFFFF0000u);
        l[j] = __float_as_uint(f[j] - hif) >> 16;
    }
    hv = make_int4((int)(h[0] | (h[1] << 16)), (int)(h[2] | (h[3] << 16)),
                   (int)(h[4] | (h[5] << 16)), (int)(h[6] | (h[7] << 16)));
    lv = make_int4((int)(l[0] | (l[1] << 16)), (int)(l[2] | (l[3] << 16)),
                   (int)(l[4] | (l[5] << 16)), (int)(l[6] | (l[7] << 16)));
}

// Device-wide sense-reversal barrier (agent-scope). All NBLK blocks co-resident.
__device__ __forceinline__ void gridbar(unsigned* cnt, unsigned* gen) {
    __syncthreads();
    if (threadIdx.x == 0) {
        __threadfence();   // release: prior writes device-visible (wbl2)
        unsigned g = __hip_atomic_load(gen, __ATOMIC_RELAXED, __HIP_MEMORY_SCOPE_AGENT);
        unsigned a = __hip_atomic_fetch_add(cnt, 1u, __ATOMIC_ACQ_REL, __HIP_MEMORY_SCOPE_AGENT);
        if (a == NBLK - 1) {
            __hip_atomic_store(cnt, 0u, __ATOMIC_RELAXED, __HIP_MEMORY_SCOPE_AGENT);
            __hip_atomic_store(gen, g + 1u, __ATOMIC_RELEASE, __HIP_MEMORY_SCOPE_AGENT);
        } else {
            while (__hip_atomic_load(gen, __ATOMIC_ACQUIRE, __HIP_MEMORY_SCOPE_AGENT) == g)
                __builtin_amdgcn_s_sleep(1);
        }
        __threadfence();   // acquire: invalidate so we see other XCDs' writes
    }
    __syncthreads();
}

// C[64b x 64n] += A[64b x K] * W[n x K]^T over nChunks*64 of K.
// A as bf16 hi/lo fragment planes: plane[(k>>3)*512 + b*8 + (k&7)].
// W fp32 row-major, row = GATES ? (r>>4)*1024 + nbase + (r&15) : nbase + r.
// 3-product split MFMA 32x32x16; wave quadrant (qr=wave>>1 -> b, qc=wave&1 -> n).
template<bool GATES>
__device__ __forceinline__ void gemm_pass(
    const float* __restrict__ W,
    const unsigned short* __restrict__ Ah, const unsigned short* __restrict__ Al,
    int nbase, int nChunks, f32x16& acc,
    short (*__restrict__ sBh)[72], short (*__restrict__ sBl)[72])
{
    const int tid = threadIdx.x;
    const int lane = tid & 63, wave = tid >> 6;
    const int lrow = lane & 31, lhalf = lane >> 5;
    const int qr = wave >> 1, qc = wave & 1;

    const int r = tid >> 2;
    const int c16 = (tid & 3) * 16;
    const int grow = GATES ? ((r >> 4) << 10) + nbase + (r & 15) : nbase + r;
    const float* wp = W + (size_t)grow * H + c16;

    {   // stage chunk 0
        float f[16];
#pragma unroll
        for (int i = 0; i < 16; i += 4) *(float4*)&f[i] = *(const float4*)&wp[i];
        int4 hv, lv;
        cvt8(&f[0], hv, lv);
        *(int4*)&sBh[r][c16] = hv; *(int4*)&sBl[r][c16] = lv;
        cvt8(&f[8], hv, lv);
        *(int4*)&sBh[r][c16 + 8] = hv; *(int4*)&sBl[r][c16 + 8] = lv;
    }
    __syncthreads();

    for (int cc = 0; cc < nChunks; ++cc) {
        const int buf = cc & 1;
        const bool pre = (cc + 1 < nChunks);
        float pf[16];
        if (pre) {
            const float* wn = wp + (cc + 1) * 64;
#pragma unroll
            for (int i = 0; i < 16; i += 4) *(float4*)&pf[i] = *(const float4*)&wn[i];
        }
        const int kgb = cc * 8 + lhalf;
#pragma unroll
        for (int kt = 0; kt < 4; ++kt) {
            const bhalf8 bh = *(const bhalf8*)&sBh[buf * 64 + qc * 32 + lrow][kt * 16 + lhalf * 8];
            const bhalf8 bl = *(const bhalf8*)&sBl[buf * 64 + qc * 32 + lrow][kt * 16 + lhalf * 8];
            const size_t aoff = (size_t)(kgb + kt * 2) * 512 + (size_t)(qr * 32 + lrow) * 8;
            const bhalf8 ah = *(const bhalf8*)(Ah + aoff);
            const bhalf8 al = *(const bhalf8*)(Al + aoff);
            acc = __builtin_amdgcn_mfma_f32_32x32x16_bf16(ah, bh, acc, 0, 0, 0);
            acc = __builtin_amdgcn_mfma_f32_32x32x16_bf16(ah, bl, acc, 0, 0, 0);
            acc = __builtin_amdgcn_mfma_f32_32x32x16_bf16(al, bh, acc, 0, 0, 0);
        }
        if (pre) {
            int4 hv, lv;
            cvt8(&pf[0], hv, lv);
            *(int4*)&sBh[(buf ^ 1) * 64 + r][c16] = hv;
            *(int4*)&sBl[(buf ^ 1) * 64 + r][c16] = lv;
            cvt8(&pf[8], hv, lv);
            *(int4*)&sBh[(buf ^ 1) * 64 + r][c16 + 8] = hv;
            *(int4*)&sBl[(buf ^ 1) * 64 + r][c16 + 8] = lv;
        }
        __syncthreads();
    }
}

__global__ void __launch_bounds__(256) k_main(
    const float* __restrict__ enc_h, const float* __restrict__ enc_c,
    const float* __restrict__ W_ih, const float* __restrict__ W_hh,
    const float* __restrict__ b_ih, const float* __restrict__ b_hh,
    const float* __restrict__ W_out, const float* __restrict__ b_out,
    const float* __restrict__ emb, const float* __restrict__ init_input,
    const int* __restrict__ eos_ptr,
    float* __restrict__ out, float* __restrict__ mask,
    float* __restrict__ candV, int* __restrict__ candI,
    unsigned short* __restrict__ xh, unsigned short* __restrict__ xl,
    unsigned short* __restrict__ hh0, unsigned short* __restrict__ hl0,
    unsigned short* __restrict__ hh1, unsigned short* __restrict__ hl1,
    unsigned* __restrict__ bar)
{
    __shared__ __align__(16) unsigned char smem[38912];
    short (*sBh)[72] = (short (*)[72])smem;              // [128][72] (2 bufs x 64 rows)
    short (*sBl)[72] = (short (*)[72])(smem + 18432);    // [128][72]
    float (*gL)[68]  = (float (*)[68])smem;              // phase-A gate exchange [64][68]
    float* redV      = (float*)smem;                     // phase-C reduce [256]
    int*   redI      = (int*)(smem + 1024);              // phase-C reduce [256]
    float* candVL    = (float*)(smem + 36864);           // [64][2]
    int*   candIL    = (int*)(smem + 37376);             // [64][2]

    const int blk = blockIdx.x;
    const int tid = threadIdx.x;
    const int gid = blk * 256 + tid;

    // ---- init: frag planes for h (enc_h, into buffer 0) and x (init_input), mask ----
    {
        int b = gid >> 10, j = gid & 1023;
        unsigned short hi, lo;
        split_trunc(enc_h[gid], hi, lo);
        size_t fo = (size_t)(j >> 3) * 512 + (size_t)b * 8 + (j & 7);
        hh0[fo] = hi; hl0[fo] = lo;
        split_trunc(init_input[j], hi, lo);
        xh[fo] = hi; xl[fo] = lo;
        if (gid < B) mask[gid] = 1.0f;
    }
    // c lives in registers of phase-A blocks: thread owns (b=tid&63, j = j0 + (tid>>6) + 4u)
    float creg[4];
    const int j0 = blk * 16;
    const int pb = tid & 63;
    const int pj = tid >> 6;
    if (blk < 64) {
#pragma unroll
        for (int u = 0; u < 4; ++u)
            creg[u] = enc_c[(size_t)pb * H + j0 + pj + u * 4];
    }
    gridbar(&bar[0], &bar[1]);

    const int lane = tid & 63, wave = tid >> 6;
    const int lrow = lane & 31, lhalf = lane >> 5;
    const int qr = wave >> 1, qc = wave & 1;

    // h double-buffer: phase A reads hA (old), writes hB (new); phase B reads hB.
    // Named-pointer swap at end of step (no runtime-indexed array -> no scratch).
    unsigned short* hA_h = hh0; unsigned short* hA_l = hl0;
    unsigned short* hB_h = hh1; unsigned short* hB_l = hl1;

    for (int t = 0; t < T; ++t) {
        // ---------- phase A: gates GEMM + LSTM pointwise (blocks 0..63) ----------
        if (blk < 64) {
            f32x16 acc;
#pragma unroll
            for (int i = 0; i < 16; ++i) acc[i] = 0.f;
            gemm_pass<true>(W_ih, xh, xl, j0, 16, acc, sBh, sBl);
            gemm_pass<true>(W_hh, hA_h, hA_l, j0, 16, acc, sBh, sBl);
            {   // scatter acc -> gates LDS (fp32), layout [b][4 gates x 16 j]
                const int col = qc * 32 + lrow;
#pragma unroll
                for (int reg = 0; reg < 16; ++reg) {
                    int row = qr * 32 + (reg & 3) + 8 * (reg >> 2) + 4 * lhalf;
                    gL[row][col] = acc[reg];
                }
            }
            __syncthreads();
#pragma unroll
            for (int u = 0; u < 4; ++u) {
                int jl = pj + u * 4;
                int jg = j0 + jl;
                float i_ = gL[pb][jl]      + b_ih[jg]          + b_hh[jg];
                float f_ = gL[pb][16 + jl] + b_ih[H + jg]      + b_hh[H + jg];
                float g_ = gL[pb][32 + jl] + b_ih[2 * H + jg]  + b_hh[2 * H + jg];
                float o_ = gL[pb][48 + jl] + b_ih[3 * H + jg]  + b_hh[3 * H + jg];
                i_ = 1.f / (1.f + expf(-i_));
                f_ = 1.f / (1.f + expf(-f_));
                g_ = tanhf(g_);
                o_ = 1.f / (1.f + expf(-o_));
                float cn = f_ * creg[u] + i_ * g_;
                float hn = o_ * tanhf(cn);
                creg[u] = cn;
                unsigned short hi, lo; split_trunc(hn, hi, lo);
                size_t fo = (size_t)(jg >> 3) * 512 + (size_t)pb * 8 + (jg & 7);
                hB_h[fo] = hi; hB_l[fo] = lo;   // write NEW buffer only
            }
        }
        gridbar(&bar[0], &bar[1]);

        // ---------- phase B: logits GEMM + bias + per-tile argmax (all blocks) ----------
        {
            const int v0 = blk * 64;
            f32x16 acc;
#pragma unroll
            for (int i = 0; i < 16; ++i) acc[i] = 0.f;
            gemm_pass<false>(W_out, hB_h, hB_l, v0, 16, acc, sBh, sBl);
            const int v = v0 + qc * 32 + lrow;
            const float bb = b_out[v];
#pragma unroll
            for (int reg = 0; reg < 16; ++reg) acc[reg] += bb;
            float* logits_t = out + TBV + (size_t)t * B * V;
#pragma unroll
            for (int reg = 0; reg < 16; ++reg) {
                int row = qr * 32 + (reg & 3) + 8 * (reg >> 2) + 4 * lhalf;
                logits_t[(size_t)row * V + v] = acc[reg];
            }
            // per-row (b) argmax across this tile's 64 cols: butterfly over the
            // 32-lane column group, then combine the two quadrant halves via LDS.
#pragma unroll
            for (int reg = 0; reg < 16; ++reg) {
                float mv = acc[reg]; int mi = v;
#pragma unroll
                for (int m = 1; m < 32; m <<= 1) {
                    float ov = __shfl_xor(mv, m);
                    int   oi = __shfl_xor(mi, m);
                    if (ov > mv || (ov == mv && oi < mi)) { mv = ov; mi = oi; }
                }
                if (lrow == 0) {
                    int row = qr * 32 + (reg & 3) + 8 * (reg >> 2) + 4 * lhalf;
                    candVL[row * 2 + qc] = mv;
                    candIL[row * 2 + qc] = mi;
                }
            }
            __syncthreads();
            if (tid < 64) {
                float va = candVL[tid * 2], vb = candVL[tid * 2 + 1];
                int   ia = candIL[tid * 2], ib = candIL[tid * 2 + 1];
                bool tk = (vb > va) || (vb == va && ib < ia);
                candV[(size_t)tid * NBLK + blk] = tk ? vb : va;
                candI[(size_t)tid * NBLK + blk] = tk ? ib : ia;
            }
        }
        gridbar(&bar[0], &bar[1]);

        // ---------- phase C: global argmax + outputs + x=emb[idx] (blocks 0..63) ----------
        if (blk < 64) {
            const int b = blk;
            redV[tid] = candV[(size_t)b * NBLK + tid];
            redI[tid] = candI[(size_t)b * NBLK + tid];
            __syncthreads();
            for (int s = 128; s > 0; s >>= 1) {
                if (tid < s) {
                    float ov = redV[tid + s]; int oi = redI[tid + s];
                    if (ov > redV[tid] || (ov == redV[tid] && oi < redI[tid])) {
                        redV[tid] = ov; redI[tid] = oi;
                    }
                }
                __syncthreads();
            }
            int idx = redI[0];
            float* predicts_t = out + (size_t)t * B * V;
            float* masks_t    = out + 2 * TBV + (size_t)t * B;
            if (tid == 0) {
                predicts_t[(size_t)b * V + idx] = 1.0f;
                masks_t[b] = mask[b];                 // old mask (pre-update)
                if (idx == *eos_ptr) mask[b] = 0.0f;
            }
            float4 e4 = *(const float4*)&emb[(size_t)idx * H + tid * 4];
            unsigned short h0, l0, h1, l1, h2, l2, h3, l3;
            split_trunc(e4.x, h0, l0); split_trunc(e4.y, h1, l1);
            split_trunc(e4.z, h2, l2); split_trunc(e4.w, h3, l3);
            int k = tid * 4;
            size_t fo = (size_t)(k >> 3) * 512 + (size_t)b * 8 + (k & 7);
            xh[fo] = h0; xh[fo + 1] = h1; xh[fo + 2] = h2; xh[fo + 3] = h3;
            xl[fo] = l0; xl[fo + 1] = l1; xl[fo + 2] = l2; xl[fo + 3] = l3;
        }
        gridbar(&bar[0], &bar[1]);

        // swap h buffers: new h becomes next step's old h
        unsigned short* th = hA_h; hA_h = hB_h; hB_h = th;
        unsigned short* tl = hA_l; hA_l = hB_l; hB_l = tl;
    }
}

extern "C" void kernel_launch(void* const* d_in, const int* in_sizes, int n_in,
                              void* d_out, int out_size, void* d_ws, size_t ws_size,
                              hipStream_t stream)
{
    (void)in_sizes; (void)n_in; (void)out_size; (void)ws_size;

    const float* enc_h = (const float*)d_in[0];
    const float* enc_c = (const float*)d_in[1];
    const float* W_ih  = (const float*)d_in[2];
    const float* W_hh  = (const float*)d_in[3];
    const float* b_ih  = (const float*)d_in[4];
    const float* b_hh  = (const float*)d_in[5];
    const float* W_out = (const float*)d_in[6];
    const float* b_out = (const float*)d_in[7];
    const float* emb   = (const float*)d_in[8];
    const float* init_input = (const float*)d_in[9];
    const int* eos_ptr = (const int*)d_in[11];   // d_in[10] = max_len (fixed T=64)

    float* out = (float*)d_out;
    char* p = (char*)d_ws;
    float* mask  = (float*)p;            p += 256;
    float* candV = (float*)p;            p += 64 * NBLK * 4;
    int*   candI = (int*)p;              p += 64 * NBLK * 4;
    unsigned short* xh  = (unsigned short*)p; p += 65536 * 2;
    unsigned short* xl  = (unsigned short*)p; p += 65536 * 2;
    unsigned short* hh0 = (unsigned short*)p; p += 65536 * 2;
    unsigned short* hl0 = (unsigned short*)p; p += 65536 * 2;
    unsigned short* hh1 = (unsigned short*)p; p += 65536 * 2;
    unsigned short* hl1 = (unsigned short*)p; p += 65536 * 2;
    unsigned* bar = (unsigned*)p;        p += 256;

    hipMemsetAsync(out, 0, TBV * sizeof(float), stream);      // predicts region
    hipMemsetAsync(bar, 0, 2 * sizeof(unsigned), stream);     // barrier state

    k_main<<<NBLK, 256, 0, stream>>>(enc_h, enc_c, W_ih, W_hh, b_ih, b_hh,
                                     W_out, b_out, emb, init_input, eos_ptr,
                                     out, mask, candV, candI, xh, xl,
                                     hh0, hl0, hh1, hl1, bar);
}

// Round 7
// 7707.690 us; speedup vs baseline: 2.7484x; 2.7484x over previous
//
#include <hip/hip_runtime.h>
#include <math.h>

#define B 64
#define H 1024
#define V 16384
#define T 64
#define NBLK 256
constexpr size_t TBV = (size_t)T * B * V;

typedef __attribute__((ext_vector_type(8))) short bhalf8;
typedef __attribute__((ext_vector_type(16))) float f32x16;

// Truncation split: a = hi + lo, hi = top-16-bits(a); total rep error ~2^-16 rel.
__device__ __forceinline__ void split_trunc(float a, unsigned short& hi, unsigned short& lo) {
    unsigned u = __float_as_uint(a);
    hi = (unsigned short)(u >> 16);
    float hif = __uint_as_float(u & 0xFFFF0000u);
    lo = (unsigned short)(__float_as_uint(a - hif) >> 16);
}

__device__ __forceinline__ void cvt8(const float* f, int4& hv, int4& lv) {
    unsigned h[8], l[8];
#pragma unroll
    for (int j = 0; j < 8; ++j) {
        unsigned u = __float_as_uint(f[j]);
        h[j] = u >> 16;
        float hif = __uint_as_float(u & 0xFFFF0000u);
        l[j] = __float_as_uint(f[j] - hif) >> 16;
    }
    hv = make_int4((int)(h[0] | (h[1] << 16)), (int)(h[2] | (h[3] << 16)),
                   (int)(h[4] | (h[5] << 16)), (int)(h[6] | (h[7] << 16)));
    lv = make_int4((int)(l[0] | (l[1] << 16)), (int)(l[2] | (l[3] << 16)),
                   (int)(l[4] | (l[5] << 16)), (int)(l[6] | (l[7] << 16)));
}

// ---------- grid barrier v2 (R4 semantics, fences hoisted out of the spin) ----------
// R4 (correct, slow): ACQUIRE load per poll iteration -> buffer_inv sc1 storm.
// v2: release fence ONCE (wbl2+waitcnt) before arrival; relaxed two-level
// monotonic arrival tree (16 groups x 16); relaxed poll + s_sleep; acquire
// fence ONCE (buffer_inv) after poll exit. Happens-before: each block's plain
// stores are flushed to IF before its arrival add; adds chain by atomic order
// to the generation publish; reader invs once after observing it.
// bar[0]=gen, bar[16+g*16]=group counters, bar[272]=top counter (all monotonic).
__device__ __forceinline__ void gridbar(unsigned* bar, unsigned bk) {
    __syncthreads();
    if (threadIdx.x == 0) {
        __builtin_amdgcn_fence(__ATOMIC_RELEASE, "agent");   // wbl2 sc1 + waitcnt, once
        unsigned* c1 = bar + 16 + (blockIdx.x >> 4) * 16;
        unsigned a1 = __hip_atomic_fetch_add(c1, 1u, __ATOMIC_RELAXED, __HIP_MEMORY_SCOPE_AGENT);
        if ((a1 & 15u) == 15u) {
            unsigned a2 = __hip_atomic_fetch_add(bar + 272, 1u, __ATOMIC_RELAXED, __HIP_MEMORY_SCOPE_AGENT);
            if ((a2 & 15u) == 15u)
                __hip_atomic_store(bar, bk, __ATOMIC_RELAXED, __HIP_MEMORY_SCOPE_AGENT);
        }
        while (__hip_atomic_load(bar, __ATOMIC_RELAXED, __HIP_MEMORY_SCOPE_AGENT) < bk)
            __builtin_amdgcn_s_sleep(8);
        __builtin_amdgcn_fence(__ATOMIC_ACQUIRE, "agent");   // buffer_inv sc1, once
    }
    __syncthreads();
}

// ---------- GEMM pass (R4-proven, plain loads): C[64b x 64n] += A * W^T ----------
// A: bf16 hi/lo planes plane[(k>>3)*512 + b*8 + (k&7)] (plain cached loads).
// W: fp32 row-major, cvt to bf16 hi/lo during LDS staging.
// 3-product split with mfma_f32_32x32x16_bf16; wave quadrant qr(b) x qc(n).
template<bool GATES>
__device__ __forceinline__ void gemm_pass(
    const float* __restrict__ W,
    const unsigned short* __restrict__ Ah, const unsigned short* __restrict__ Al,
    int nbase, f32x16& acc,
    short (*__restrict__ sBh)[72], short (*__restrict__ sBl)[72])
{
    const int tid = threadIdx.x;
    const int lane = tid & 63, wave = tid >> 6;
    const int lrow = lane & 31, lhalf = lane >> 5;
    const int qr = wave >> 1, qc = wave & 1;

    const int r = tid >> 2;
    const int c16 = (tid & 3) * 16;
    const int grow = GATES ? ((r >> 4) << 10) + nbase + (r & 15) : nbase + r;
    const float* wp = W + (size_t)grow * H + c16;

    {   // stage chunk 0
        float f[16];
#pragma unroll
        for (int i = 0; i < 16; i += 4) *(float4*)&f[i] = *(const float4*)&wp[i];
        int4 hv, lv;
        cvt8(&f[0], hv, lv);
        *(int4*)&sBh[r][c16] = hv; *(int4*)&sBl[r][c16] = lv;
        cvt8(&f[8], hv, lv);
        *(int4*)&sBh[r][c16 + 8] = hv; *(int4*)&sBl[r][c16 + 8] = lv;
    }
    __syncthreads();

    for (int cc = 0; cc < 16; ++cc) {
        const int buf = cc & 1;
        const bool pre = (cc + 1 < 16);
        float pf[16];
        if (pre) {   // issue next W chunk's loads early (hide under MFMA)
            const float* wn = wp + (cc + 1) * 64;
#pragma unroll
            for (int i = 0; i < 16; i += 4) *(float4*)&pf[i] = *(const float4*)&wn[i];
        }
        const int kgb = cc * 8 + lhalf;
#pragma unroll
        for (int kt = 0; kt < 4; ++kt) {
            const bhalf8 bh = *(const bhalf8*)&sBh[buf * 64 + qc * 32 + lrow][kt * 16 + lhalf * 8];
            const bhalf8 bl = *(const bhalf8*)&sBl[buf * 64 + qc * 32 + lrow][kt * 16 + lhalf * 8];
            const size_t aoff = (size_t)(kgb + kt * 2) * 512 + (size_t)(qr * 32 + lrow) * 8;
            const bhalf8 ah = *(const bhalf8*)(Ah + aoff);
            const bhalf8 al = *(const bhalf8*)(Al + aoff);
            acc = __builtin_amdgcn_mfma_f32_32x32x16_bf16(ah, bh, acc, 0, 0, 0);
            acc = __builtin_amdgcn_mfma_f32_32x32x16_bf16(ah, bl, acc, 0, 0, 0);
            acc = __builtin_amdgcn_mfma_f32_32x32x16_bf16(al, bh, acc, 0, 0, 0);
        }
        if (pre) {
            int4 hv, lv;
            cvt8(&pf[0], hv, lv);
            *(int4*)&sBh[(buf ^ 1) * 64 + r][c16] = hv;
            *(int4*)&sBl[(buf ^ 1) * 64 + r][c16] = lv;
            cvt8(&pf[8], hv, lv);
            *(int4*)&sBh[(buf ^ 1) * 64 + r][c16 + 8] = hv;
            *(int4*)&sBl[(buf ^ 1) * 64 + r][c16 + 8] = lv;
        }
        __syncthreads();
    }
}

__global__ void __launch_bounds__(256) k_main(
    const float* __restrict__ enc_h, const float* __restrict__ enc_c,
    const float* __restrict__ W_ih, const float* __restrict__ W_hh,
    const float* __restrict__ b_ih, const float* __restrict__ b_hh,
    const float* __restrict__ W_out, const float* __restrict__ b_out,
    const float* __restrict__ emb, const float* __restrict__ init_input,
    const int* __restrict__ eos_ptr,
    float* __restrict__ out, float* __restrict__ mask,
    float* __restrict__ candV, int* __restrict__ candI,
    unsigned short* __restrict__ xh, unsigned short* __restrict__ xl,
    unsigned short* __restrict__ hh0, unsigned short* __restrict__ hl0,
    unsigned short* __restrict__ hh1, unsigned short* __restrict__ hl1,
    unsigned* __restrict__ bar)
{
    __shared__ __align__(16) unsigned char smem[38912];
    short (*sBh)[72] = (short (*)[72])smem;              // [128][72] (2 bufs x 64 rows)
    short (*sBl)[72] = (short (*)[72])(smem + 18432);    // [128][72]
    float (*gL)[68]  = (float (*)[68])smem;              // phase-A gate exchange (aliases sBh)
    float* redV      = (float*)smem;                     // phase-C reduce [256]
    int*   redI      = (int*)(smem + 1024);              // phase-C reduce [256]
    float* candVL    = (float*)(smem + 36864);           // [64][2]
    int*   candIL    = (int*)(smem + 37376);             // [64][2]

    const int blk = blockIdx.x;
    const int tid = threadIdx.x;
    const int gid = blk * 256 + tid;

    // ---- init: frag planes for h (enc_h, buffer 0) and x (init_input), mask ----
    {
        int b = gid >> 10, j = gid & 1023;
        unsigned short hi, lo;
        split_trunc(enc_h[gid], hi, lo);
        size_t fo = (size_t)(j >> 3) * 512 + (size_t)b * 8 + (j & 7);
        hh0[fo] = hi; hl0[fo] = lo;
        split_trunc(init_input[j], hi, lo);
        xh[fo] = hi; xl[fo] = lo;
        if (gid < B) mask[gid] = 1.0f;
    }
    // c lives in registers of phase-A blocks: thread owns (b=tid&63, j=j0+(tid>>6)+4u)
    float creg[4];
    const int j0 = blk * 16;
    const int pb = tid & 63;
    const int pj = tid >> 6;
    if (blk < 64) {
#pragma unroll
        for (int u = 0; u < 4; ++u)
            creg[u] = enc_c[(size_t)pb * H + j0 + pj + u * 4];
    }
    unsigned bk = 1;
    gridbar(bar, bk);

    const int lane = tid & 63, wave = tid >> 6;
    const int lrow = lane & 31, lhalf = lane >> 5;
    const int qr = wave >> 1, qc = wave & 1;

    // h double-buffer: phase A reads hA (old), writes hB (new); phase B reads hB.
    unsigned short* hA_h = hh0; unsigned short* hA_l = hl0;
    unsigned short* hB_h = hh1; unsigned short* hB_l = hl1;

    for (int t = 0; t < T; ++t) {
        // ---------- phase A: gates GEMM + LSTM pointwise (blocks 0..63) ----------
        if (blk < 64) {
            f32x16 acc;
#pragma unroll
            for (int i = 0; i < 16; ++i) acc[i] = 0.f;
            gemm_pass<true>(W_ih, xh, xl, j0, acc, sBh, sBl);
            gemm_pass<true>(W_hh, hA_h, hA_l, j0, acc, sBh, sBl);
            {   // scatter acc -> gates LDS (fp32), layout [b][4 gates x 16 j]
                const int col = qc * 32 + lrow;
#pragma unroll
                for (int reg = 0; reg < 16; ++reg) {
                    int row = qr * 32 + (reg & 3) + 8 * (reg >> 2) + 4 * lhalf;
                    gL[row][col] = acc[reg];
                }
            }
            __syncthreads();
#pragma unroll
            for (int u = 0; u < 4; ++u) {
                int jl = pj + u * 4;
                int jg = j0 + jl;
                float i_ = gL[pb][jl]      + b_ih[jg]          + b_hh[jg];
                float f_ = gL[pb][16 + jl] + b_ih[H + jg]      + b_hh[H + jg];
                float g_ = gL[pb][32 + jl] + b_ih[2 * H + jg]  + b_hh[2 * H + jg];
                float o_ = gL[pb][48 + jl] + b_ih[3 * H + jg]  + b_hh[3 * H + jg];
                i_ = 1.f / (1.f + expf(-i_));
                f_ = 1.f / (1.f + expf(-f_));
                g_ = tanhf(g_);
                o_ = 1.f / (1.f + expf(-o_));
                float cn = f_ * creg[u] + i_ * g_;
                float hn = o_ * tanhf(cn);
                creg[u] = cn;
                unsigned short hi, lo; split_trunc(hn, hi, lo);
                size_t fo = (size_t)(jg >> 3) * 512 + (size_t)pb * 8 + (jg & 7);
                hB_h[fo] = hi; hB_l[fo] = lo;   // write NEW buffer only
            }
        }
        gridbar(bar, ++bk);

        // ---------- phase B: logits GEMM + bias + per-tile argmax (all 256 blocks) ----------
        {
            const int v0 = blk * 64;
            f32x16 acc;
#pragma unroll
            for (int i = 0; i < 16; ++i) acc[i] = 0.f;
            gemm_pass<false>(W_out, hB_h, hB_l, v0, acc, sBh, sBl);
            const int v = v0 + qc * 32 + lrow;
            const float bb = b_out[v];
#pragma unroll
            for (int reg = 0; reg < 16; ++reg) acc[reg] += bb;
            float* logits_t = out + TBV + (size_t)t * B * V;
#pragma unroll
            for (int reg = 0; reg < 16; ++reg) {
                int row = qr * 32 + (reg & 3) + 8 * (reg >> 2) + 4 * lhalf;
                logits_t[(size_t)row * V + v] = acc[reg];
            }
            // per-row argmax across this tile's 64 cols: butterfly over the
            // 32-lane column group, then combine the two quadrant halves via LDS.
#pragma unroll
            for (int reg = 0; reg < 16; ++reg) {
                float mv = acc[reg]; int mi = v;
#pragma unroll
                for (int m = 1; m < 32; m <<= 1) {
                    float ov = __shfl_xor(mv, m);
                    int   oi = __shfl_xor(mi, m);
                    if (ov > mv || (ov == mv && oi < mi)) { mv = ov; mi = oi; }
                }
                if (lrow == 0) {
                    int row = qr * 32 + (reg & 3) + 8 * (reg >> 2) + 4 * lhalf;
                    candVL[row * 2 + qc] = mv;
                    candIL[row * 2 + qc] = mi;
                }
            }
            __syncthreads();
            if (tid < 64) {
                float va = candVL[tid * 2], vb = candVL[tid * 2 + 1];
                int   ia = candIL[tid * 2], ib = candIL[tid * 2 + 1];
                bool tk = (vb > va) || (vb == va && ib < ia);
                candV[(size_t)tid * NBLK + blk] = tk ? vb : va;
                candI[(size_t)tid * NBLK + blk] = tk ? ib : ia;
            }
        }
        gridbar(bar, ++bk);

        // ---------- phase C: global argmax + outputs + x=emb[idx] (blocks 0..63) ----------
        if (blk < 64) {
            const int b = blk;
            redV[tid] = candV[(size_t)b * NBLK + tid];
            redI[tid] = candI[(size_t)b * NBLK + tid];
            __syncthreads();
            for (int s = 128; s > 0; s >>= 1) {
                if (tid < s) {
                    float ov = redV[tid + s]; int oi = redI[tid + s];
                    if (ov > redV[tid] || (ov == redV[tid] && oi < redI[tid])) {
                        redV[tid] = ov; redI[tid] = oi;
                    }
                }
                __syncthreads();
            }
            int idx = redI[0];
            float* predicts_t = out + (size_t)t * B * V;
            float* masks_t    = out + 2 * TBV + (size_t)t * B;
            if (tid == 0) {
                predicts_t[(size_t)b * V + idx] = 1.0f;
                masks_t[b] = mask[b];                 // old mask (pre-update)
                if (idx == *eos_ptr) mask[b] = 0.0f;
            }
            float4 e4 = *(const float4*)&emb[(size_t)idx * H + tid * 4];
            unsigned short h0, l0, h1, l1, h2, l2, h3, l3;
            split_trunc(e4.x, h0, l0); split_trunc(e4.y, h1, l1);
            split_trunc(e4.z, h2, l2); split_trunc(e4.w, h3, l3);
            int k = tid * 4;
            size_t fo = (size_t)(k >> 3) * 512 + (size_t)b * 8 + (k & 7);
            xh[fo] = h0; xh[fo + 1] = h1; xh[fo + 2] = h2; xh[fo + 3] = h3;
            xl[fo] = l0; xl[fo + 1] = l1; xl[fo + 2] = l2; xl[fo + 3] = l3;
        }
        gridbar(bar, ++bk);

        // swap h buffers: new h becomes next step's old h
        unsigned short* th = hA_h; hA_h = hB_h; hB_h = th;
        unsigned short* tl = hA_l; hA_l = hB_l; hB_l = tl;
    }
}

extern "C" void kernel_launch(void* const* d_in, const int* in_sizes, int n_in,
                              void* d_out, int out_size, void* d_ws, size_t ws_size,
                              hipStream_t stream)
{
    (void)in_sizes; (void)n_in; (void)out_size; (void)ws_size;

    const float* enc_h = (const float*)d_in[0];
    const float* enc_c = (const float*)d_in[1];
    const float* W_ih  = (const float*)d_in[2];
    const float* W_hh  = (const float*)d_in[3];
    const float* b_ih  = (const float*)d_in[4];
    const float* b_hh  = (const float*)d_in[5];
    const float* W_out = (const float*)d_in[6];
    const float* b_out = (const float*)d_in[7];
    const float* emb   = (const float*)d_in[8];
    const float* init_input = (const float*)d_in[9];
    const int* eos_ptr = (const int*)d_in[11];   // d_in[10] = max_len (fixed T=64)

    float* out = (float*)d_out;
    char* p = (char*)d_ws;
    float* mask  = (float*)p;                 p += 256;
    float* candV = (float*)p;                 p += 64 * NBLK * 4;
    int*   candI = (int*)p;                   p += 64 * NBLK * 4;
    unsigned short* xh  = (unsigned short*)p; p += 65536 * 2;
    unsigned short* xl  = (unsigned short*)p; p += 65536 * 2;
    unsigned short* hh0 = (unsigned short*)p; p += 65536 * 2;
    unsigned short* hl0 = (unsigned short*)p; p += 65536 * 2;
    unsigned short* hh1 = (unsigned short*)p; p += 65536 * 2;
    unsigned short* hl1 = (unsigned short*)p; p += 65536 * 2;
    unsigned* bar = (unsigned*)p;             p += 2048;

    hipMemsetAsync(out, 0, TBV * sizeof(float), stream);   // predicts region
    hipMemsetAsync(bar, 0, 2048, stream);                  // barrier counters

    k_main<<<NBLK, 256, 0, stream>>>(enc_h, enc_c, W_ih, W_hh, b_ih, b_hh,
                                     W_out, b_out, emb, init_input, eos_ptr,
                                     out, mask, candV, candI, xh, xl,
                                     hh0, hl0, hh1, hl1, bar);
}

// Round 8
// 6638.100 us; speedup vs baseline: 3.1913x; 1.1611x over previous
//
#include <hip/hip_runtime.h>
#include <math.h>

#define B 64
#define H 1024
#define V 16384
#define T 64
#define NBLK 256
constexpr size_t TBV = (size_t)T * B * V;

typedef __attribute__((ext_vector_type(8))) short bhalf8;
typedef __attribute__((ext_vector_type(16))) float f32x16;
typedef __attribute__((ext_vector_type(4))) int i32x4;

// Truncation split: a = hi + lo, hi = top-16-bits(a); total rep error ~2^-16 rel.
__device__ __forceinline__ void split_trunc(float a, unsigned short& hi, unsigned short& lo) {
    unsigned u = __float_as_uint(a);
    hi = (unsigned short)(u >> 16);
    float hif = __uint_as_float(u & 0xFFFF0000u);
    lo = (unsigned short)(__float_as_uint(a - hif) >> 16);
}

__device__ __forceinline__ void cvt8(const float* f, int4& hv, int4& lv) {
    unsigned h[8], l[8];
#pragma unroll
    for (int j = 0; j < 8; ++j) {
        unsigned u = __float_as_uint(f[j]);
        h[j] = u >> 16;
        float hif = __uint_as_float(u & 0xFFFF0000u);
        l[j] = __float_as_uint(f[j] - hif) >> 16;
    }
    hv = make_int4((int)(h[0] | (h[1] << 16)), (int)(h[2] | (h[3] << 16)),
                   (int)(h[4] | (h[5] << 16)), (int)(h[6] | (h[7] << 16)));
    lv = make_int4((int)(l[0] | (l[1] << 16)), (int)(l[2] | (l[3] << 16)),
                   (int)(l[4] | (l[5] << 16)), (int)(l[6] | (l[7] << 16)));
}

// ---------- coherent readers: bypass L1+L2, read from IF ----------
// Writers stay PLAIN stores; the barrier's release fence (wbl2+waitcnt) makes
// them IF-visible before arrival. Readers bypass their (possibly stale) L2.
// No buffer_inv anywhere -> weights stay L2-resident.
__device__ __forceinline__ void load_a_chunk(
    const unsigned short* ph, const unsigned short* pl,
    i32x4& h0, i32x4& h1, i32x4& h2, i32x4& h3,
    i32x4& l0, i32x4& l1, i32x4& l2, i32x4& l3)
{
    asm volatile(
        "global_load_dwordx4 %0, %8, off sc0 sc1\n\t"
        "global_load_dwordx4 %1, %9, off sc0 sc1\n\t"
        "global_load_dwordx4 %2, %10, off sc0 sc1\n\t"
        "global_load_dwordx4 %3, %11, off sc0 sc1\n\t"
        "global_load_dwordx4 %4, %12, off sc0 sc1\n\t"
        "global_load_dwordx4 %5, %13, off sc0 sc1\n\t"
        "global_load_dwordx4 %6, %14, off sc0 sc1\n\t"
        "global_load_dwordx4 %7, %15, off sc0 sc1\n\t"
        "s_waitcnt vmcnt(0)"
        : "=&v"(h0), "=&v"(h1), "=&v"(h2), "=&v"(h3),
          "=&v"(l0), "=&v"(l1), "=&v"(l2), "=&v"(l3)
        : "v"(ph), "v"(ph + 1024), "v"(ph + 2048), "v"(ph + 3072),
          "v"(pl), "v"(pl + 1024), "v"(pl + 2048), "v"(pl + 3072)
        : "memory");
}

__device__ __forceinline__ void ld_sc2(const float* pv, const int* pi, float& v, int& ii) {
    asm volatile(
        "global_load_dword %0, %2, off sc0 sc1\n\t"
        "global_load_dword %1, %3, off sc0 sc1\n\t"
        "s_waitcnt vmcnt(0)"
        : "=&v"(v), "=&v"(ii)
        : "v"(pv), "v"(pi)
        : "memory");
}

// ---------- grid barrier v3: release fence kept (R7-proven), acquire inv REMOVED ----------
// bar[0]=gen, bar[16+g*16]=group counters, bar[272]=top counter (all monotonic).
// Happens-before: each block's plain stores are wbl2-flushed to IF before its
// relaxed arrival add (fence orders store->RMW); adds chain by atomic order +
// control dependency to the generation publish; readers poll (relaxed), then
// read shared data with sc0sc1 loads that bypass L2 -> no stale reads, no inv.
__device__ __forceinline__ void gridbar(unsigned* bar, unsigned bk) {
    __syncthreads();
    if (threadIdx.x == 0) {
        __builtin_amdgcn_fence(__ATOMIC_RELEASE, "agent");   // waitcnt + wbl2, once
        unsigned* c1 = bar + 16 + (blockIdx.x >> 4) * 16;
        unsigned a1 = __hip_atomic_fetch_add(c1, 1u, __ATOMIC_RELAXED, __HIP_MEMORY_SCOPE_AGENT);
        if ((a1 & 15u) == 15u) {
            unsigned a2 = __hip_atomic_fetch_add(bar + 272, 1u, __ATOMIC_RELAXED, __HIP_MEMORY_SCOPE_AGENT);
            if ((a2 & 15u) == 15u)
                __hip_atomic_store(bar, bk, __ATOMIC_RELAXED, __HIP_MEMORY_SCOPE_AGENT);
        }
        while (__hip_atomic_load(bar, __ATOMIC_RELAXED, __HIP_MEMORY_SCOPE_AGENT) < bk)
            __builtin_amdgcn_s_sleep(8);
    }
    __syncthreads();
}

// ---------- GEMM pass: C[64b x 64n] += A[64b x 1024k] * W[n x k]^T ----------
// A: bf16 hi/lo planes plane[(k>>3)*512 + b*8 + (k&7)], read via sc0sc1 (IF).
// W: fp32 row-major, PLAIN cached loads (L2-resident), cvt to bf16 hi/lo in LDS.
// 3-product split with mfma_f32_32x32x16_bf16; wave quadrant qr(b) x qc(n).
template<bool GATES>
__device__ __forceinline__ void gemm_pass(
    const float* __restrict__ W,
    const unsigned short* __restrict__ Ah, const unsigned short* __restrict__ Al,
    int nbase, f32x16& acc,
    short (*__restrict__ sBh)[72], short (*__restrict__ sBl)[72])
{
    const int tid = threadIdx.x;
    const int lane = tid & 63, wave = tid >> 6;
    const int lrow = lane & 31, lhalf = lane >> 5;
    const int qr = wave >> 1, qc = wave & 1;

    const int r = tid >> 2;
    const int c16 = (tid & 3) * 16;
    const int grow = GATES ? ((r >> 4) << 10) + nbase + (r & 15) : nbase + r;
    const float* wp = W + (size_t)grow * H + c16;

    const unsigned short* pAh = Ah + (size_t)lhalf * 512 + (size_t)(qr * 32 + lrow) * 8;
    const unsigned short* pAl = Al + (size_t)lhalf * 512 + (size_t)(qr * 32 + lrow) * 8;

    {   // stage chunk 0
        float f[16];
#pragma unroll
        for (int i = 0; i < 16; i += 4) *(float4*)&f[i] = *(const float4*)&wp[i];
        int4 hv, lv;
        cvt8(&f[0], hv, lv);
        *(int4*)&sBh[r][c16] = hv; *(int4*)&sBl[r][c16] = lv;
        cvt8(&f[8], hv, lv);
        *(int4*)&sBh[r][c16 + 8] = hv; *(int4*)&sBl[r][c16 + 8] = lv;
    }
    __syncthreads();

    for (int cc = 0; cc < 16; ++cc) {
        const int buf = cc & 1;
        const bool pre = (cc + 1 < 16);
        float pf[16];
        if (pre) {   // issue next W chunk's loads early (overlap with A IF-latency)
            const float* wn = wp + (cc + 1) * 64;
#pragma unroll
            for (int i = 0; i < 16; i += 4) *(float4*)&pf[i] = *(const float4*)&wn[i];
        }
        i32x4 vh[4], vl[4];
        load_a_chunk(pAh + cc * 4096, pAl + cc * 4096,
                     vh[0], vh[1], vh[2], vh[3], vl[0], vl[1], vl[2], vl[3]);
#pragma unroll
        for (int kt = 0; kt < 4; ++kt) {
            const bhalf8 bh = *(const bhalf8*)&sBh[buf * 64 + qc * 32 + lrow][kt * 16 + lhalf * 8];
            const bhalf8 bl = *(const bhalf8*)&sBl[buf * 64 + qc * 32 + lrow][kt * 16 + lhalf * 8];
            const bhalf8 ah = __builtin_bit_cast(bhalf8, vh[kt]);
            const bhalf8 al = __builtin_bit_cast(bhalf8, vl[kt]);
            acc = __builtin_amdgcn_mfma_f32_32x32x16_bf16(ah, bh, acc, 0, 0, 0);
            acc = __builtin_amdgcn_mfma_f32_32x32x16_bf16(ah, bl, acc, 0, 0, 0);
            acc = __builtin_amdgcn_mfma_f32_32x32x16_bf16(al, bh, acc, 0, 0, 0);
        }
        if (pre) {
            int4 hv, lv;
            cvt8(&pf[0], hv, lv);
            *(int4*)&sBh[(buf ^ 1) * 64 + r][c16] = hv;
            *(int4*)&sBl[(buf ^ 1) * 64 + r][c16] = lv;
            cvt8(&pf[8], hv, lv);
            *(int4*)&sBh[(buf ^ 1) * 64 + r][c16 + 8] = hv;
            *(int4*)&sBl[(buf ^ 1) * 64 + r][c16 + 8] = lv;
        }
        __syncthreads();
    }
}

__global__ void __launch_bounds__(256) k_main(
    const float* __restrict__ enc_h, const float* __restrict__ enc_c,
    const float* __restrict__ W_ih, const float* __restrict__ W_hh,
    const float* __restrict__ b_ih, const float* __restrict__ b_hh,
    const float* __restrict__ W_out, const float* __restrict__ b_out,
    const float* __restrict__ emb, const float* __restrict__ init_input,
    const int* __restrict__ eos_ptr,
    float* __restrict__ out, float* __restrict__ mask,
    float* __restrict__ candV, int* __restrict__ candI,
    unsigned short* __restrict__ xh, unsigned short* __restrict__ xl,
    unsigned short* __restrict__ hh0, unsigned short* __restrict__ hl0,
    unsigned short* __restrict__ hh1, unsigned short* __restrict__ hl1,
    unsigned* __restrict__ bar)
{
    __shared__ __align__(16) unsigned char smem[38912];
    short (*sBh)[72] = (short (*)[72])smem;              // [128][72] (2 bufs x 64 rows)
    short (*sBl)[72] = (short (*)[72])(smem + 18432);    // [128][72]
    float (*gL)[68]  = (float (*)[68])smem;              // phase-A gate exchange (aliases sBh)
    float* redV      = (float*)smem;                     // phase-C reduce [256]
    int*   redI      = (int*)(smem + 1024);              // phase-C reduce [256]
    float* candVL    = (float*)(smem + 36864);           // [64][2]
    int*   candIL    = (int*)(smem + 37376);             // [64][2]

    const int blk = blockIdx.x;
    const int tid = threadIdx.x;
    const int gid = blk * 256 + tid;

    // ---- init: frag planes for h (enc_h, buffer 0) and x (init_input), mask ----
    {
        int b = gid >> 10, j = gid & 1023;
        unsigned short hi, lo;
        split_trunc(enc_h[gid], hi, lo);
        size_t fo = (size_t)(j >> 3) * 512 + (size_t)b * 8 + (j & 7);
        hh0[fo] = hi; hl0[fo] = lo;
        split_trunc(init_input[j], hi, lo);
        xh[fo] = hi; xl[fo] = lo;
        if (gid < B) mask[gid] = 1.0f;
    }
    // c lives in registers of phase-A blocks: thread owns (b=tid&63, j=j0+(tid>>6)+4u)
    float creg[4];
    const int j0 = blk * 16;
    const int pb = tid & 63;
    const int pj = tid >> 6;
    if (blk < 64) {
#pragma unroll
        for (int u = 0; u < 4; ++u)
            creg[u] = enc_c[(size_t)pb * H + j0 + pj + u * 4];
    }
    unsigned bk = 1;
    gridbar(bar, bk);

    const int lane = tid & 63, wave = tid >> 6;
    const int lrow = lane & 31, lhalf = lane >> 5;
    const int qr = wave >> 1, qc = wave & 1;

    // h double-buffer: phase A reads hA (old), writes hB (new); phase B reads hB.
    unsigned short* hA_h = hh0; unsigned short* hA_l = hl0;
    unsigned short* hB_h = hh1; unsigned short* hB_l = hl1;

    for (int t = 0; t < T; ++t) {
        // ---------- phase A: gates GEMM + LSTM pointwise (blocks 0..63) ----------
        if (blk < 64) {
            f32x16 acc;
#pragma unroll
            for (int i = 0; i < 16; ++i) acc[i] = 0.f;
            gemm_pass<true>(W_ih, xh, xl, j0, acc, sBh, sBl);
            gemm_pass<true>(W_hh, hA_h, hA_l, j0, acc, sBh, sBl);
            {   // scatter acc -> gates LDS (fp32), layout [b][4 gates x 16 j]
                const int col = qc * 32 + lrow;
#pragma unroll
                for (int reg = 0; reg < 16; ++reg) {
                    int row = qr * 32 + (reg & 3) + 8 * (reg >> 2) + 4 * lhalf;
                    gL[row][col] = acc[reg];
                }
            }
            __syncthreads();
#pragma unroll
            for (int u = 0; u < 4; ++u) {
                int jl = pj + u * 4;
                int jg = j0 + jl;
                float i_ = gL[pb][jl]      + b_ih[jg]          + b_hh[jg];
                float f_ = gL[pb][16 + jl] + b_ih[H + jg]      + b_hh[H + jg];
                float g_ = gL[pb][32 + jl] + b_ih[2 * H + jg]  + b_hh[2 * H + jg];
                float o_ = gL[pb][48 + jl] + b_ih[3 * H + jg]  + b_hh[3 * H + jg];
                i_ = 1.f / (1.f + expf(-i_));
                f_ = 1.f / (1.f + expf(-f_));
                g_ = tanhf(g_);
                o_ = 1.f / (1.f + expf(-o_));
                float cn = f_ * creg[u] + i_ * g_;
                float hn = o_ * tanhf(cn);
                creg[u] = cn;
                unsigned short hi, lo; split_trunc(hn, hi, lo);
                size_t fo = (size_t)(jg >> 3) * 512 + (size_t)pb * 8 + (jg & 7);
                hB_h[fo] = hi; hB_l[fo] = lo;   // write NEW buffer only (plain store)
            }
        }
        gridbar(bar, ++bk);

        // ---------- phase B: logits GEMM + bias + per-tile argmax (all 256 blocks) ----------
        {
            const int v0 = blk * 64;
            f32x16 acc;
#pragma unroll
            for (int i = 0; i < 16; ++i) acc[i] = 0.f;
            gemm_pass<false>(W_out, hB_h, hB_l, v0, acc, sBh, sBl);
            const int v = v0 + qc * 32 + lrow;
            const float bb = b_out[v];
#pragma unroll
            for (int reg = 0; reg < 16; ++reg) acc[reg] += bb;
            float* logits_t = out + TBV + (size_t)t * B * V;
#pragma unroll
            for (int reg = 0; reg < 16; ++reg) {
                int row = qr * 32 + (reg & 3) + 8 * (reg >> 2) + 4 * lhalf;
                logits_t[(size_t)row * V + v] = acc[reg];
            }
            // per-row argmax across this tile's 64 cols: butterfly over the
            // 32-lane column group, then combine the two quadrant halves via LDS.
#pragma unroll
            for (int reg = 0; reg < 16; ++reg) {
                float mv = acc[reg]; int mi = v;
#pragma unroll
                for (int m = 1; m < 32; m <<= 1) {
                    float ov = __shfl_xor(mv, m);
                    int   oi = __shfl_xor(mi, m);
                    if (ov > mv || (ov == mv && oi < mi)) { mv = ov; mi = oi; }
                }
                if (lrow == 0) {
                    int row = qr * 32 + (reg & 3) + 8 * (reg >> 2) + 4 * lhalf;
                    candVL[row * 2 + qc] = mv;
                    candIL[row * 2 + qc] = mi;
                }
            }
            __syncthreads();
            if (tid < 64) {
                float va = candVL[tid * 2], vb = candVL[tid * 2 + 1];
                int   ia = candIL[tid * 2], ib = candIL[tid * 2 + 1];
                bool tk = (vb > va) || (vb == va && ib < ia);
                candV[(size_t)tid * NBLK + blk] = tk ? vb : va;   // plain store
                candI[(size_t)tid * NBLK + blk] = tk ? ib : ia;   // plain store
            }
        }
        gridbar(bar, ++bk);

        // ---------- phase C: global argmax + outputs + x=emb[idx] (blocks 0..63) ----------
        if (blk < 64) {
            const int b = blk;
            float cv; int ci;
            ld_sc2(&candV[(size_t)b * NBLK + tid], &candI[(size_t)b * NBLK + tid], cv, ci);
            redV[tid] = cv;
            redI[tid] = ci;
            __syncthreads();
            for (int s = 128; s > 0; s >>= 1) {
                if (tid < s) {
                    float ov = redV[tid + s]; int oi = redI[tid + s];
                    if (ov > redV[tid] || (ov == redV[tid] && oi < redI[tid])) {
                        redV[tid] = ov; redI[tid] = oi;
                    }
                }
                __syncthreads();
            }
            int idx = redI[0];
            float* predicts_t = out + (size_t)t * B * V;
            float* masks_t    = out + 2 * TBV + (size_t)t * B;
            if (tid == 0) {
                predicts_t[(size_t)b * V + idx] = 1.0f;
                masks_t[b] = mask[b];                 // old mask (pre-update)
                if (idx == *eos_ptr) mask[b] = 0.0f;
            }
            float4 e4 = *(const float4*)&emb[(size_t)idx * H + tid * 4];
            unsigned short h0, l0, h1, l1, h2, l2, h3, l3;
            split_trunc(e4.x, h0, l0); split_trunc(e4.y, h1, l1);
            split_trunc(e4.z, h2, l2); split_trunc(e4.w, h3, l3);
            int k = tid * 4;
            size_t fo = (size_t)(k >> 3) * 512 + (size_t)b * 8 + (k & 7);
            xh[fo] = h0; xh[fo + 1] = h1; xh[fo + 2] = h2; xh[fo + 3] = h3;
            xl[fo] = l0; xl[fo + 1] = l1; xl[fo + 2] = l2; xl[fo + 3] = l3;
        }
        gridbar(bar, ++bk);

        // swap h buffers: new h becomes next step's old h
        unsigned short* th = hA_h; hA_h = hB_h; hB_h = th;
        unsigned short* tl = hA_l; hA_l = hB_l; hB_l = tl;
    }
}

extern "C" void kernel_launch(void* const* d_in, const int* in_sizes, int n_in,
                              void* d_out, int out_size, void* d_ws, size_t ws_size,
                              hipStream_t stream)
{
    (void)in_sizes; (void)n_in; (void)out_size; (void)ws_size;

    const float* enc_h = (const float*)d_in[0];
    const float* enc_c = (const float*)d_in[1];
    const float* W_ih  = (const float*)d_in[2];
    const float* W_hh  = (const float*)d_in[3];
    const float* b_ih  = (const float*)d_in[4];
    const float* b_hh  = (const float*)d_in[5];
    const float* W_out = (const float*)d_in[6];
    const float* b_out = (const float*)d_in[7];
    const float* emb   = (const float*)d_in[8];
    const float* init_input = (const float*)d_in[9];
    const int* eos_ptr = (const int*)d_in[11];   // d_in[10] = max_len (fixed T=64)

    float* out = (float*)d_out;
    char* p = (char*)d_ws;
    float* mask  = (float*)p;                 p += 256;
    float* candV = (float*)p;                 p += 64 * NBLK * 4;
    int*   candI = (int*)p;                   p += 64 * NBLK * 4;
    unsigned short* xh  = (unsigned short*)p; p += 65536 * 2;
    unsigned short* xl  = (unsigned short*)p; p += 65536 * 2;
    unsigned short* hh0 = (unsigned short*)p; p += 65536 * 2;
    unsigned short* hl0 = (unsigned short*)p; p += 65536 * 2;
    unsigned short* hh1 = (unsigned short*)p; p += 65536 * 2;
    unsigned short* hl1 = (unsigned short*)p; p += 65536 * 2;
    unsigned* bar = (unsigned*)p;             p += 2048;

    hipMemsetAsync(out, 0, TBV * sizeof(float), stream);   // predicts region
    hipMemsetAsync(bar, 0, 2048, stream);                  // barrier counters

    k_main<<<NBLK, 256, 0, stream>>>(enc_h, enc_c, W_ih, W_hh, b_ih, b_hh,
                                     W_out, b_out, emb, init_input, eos_ptr,
                                     out, mask, candV, candI, xh, xl,
                                     hh0, hl0, hh1, hl1, bar);
}